// Round 9
// baseline (173.889 us; speedup 1.0000x reference)
//
#include <hip/hip_runtime.h>
#include <math.h>

// Geometry: seg_out/logits (2,4,128,128,128) f32, y (2,1,128,128,128) i32,
// calib (20,4) f32, weight scalar int. Output: 1 f32 scalar.
#define VB 2097152            // voxels per (batch, channel) = 128^3
#define QB (VB / 4)           // float4 quads per (batch, channel)
#define NBINS 20

// NO-ATOMIC accumulation: each block WRITES its partials into a private slot.
//   float region: counter (b*20+row) x 512 slots  -> 40*512 words
//   hist  region: counter (cc*40+kind*20+bin) x 1024 slots -> 80*1024 words
// No ws memset needed (poison overwritten), no global atomics, 2 dispatches.
#define FSLOTS 512
#define HSLOTS 1024
#define HB (40 * FSLOTS)                    // word offset of hist region (20480)
#define WS_WORDS (HB + 80 * HSLOTS)         // 102400 words = 400 KiB

// Privatized LDS histogram: 8 copies, stride 81 words (odd => distinct banks).
#define HCOPIES 8
#define HSTRIDE 81

#define NBLK 1024
#define BPB 512
#define QSTRIDE (BPB * 256)    // 131072; KITER * QSTRIDE == QB
#define KITER 4

__device__ __forceinline__ float sel(const float4 v, int j) {
    return j == 0 ? v.x : (j == 1 ? v.y : (j == 2 ? v.z : v.w));
}
__device__ __forceinline__ int seli(const int4 v, int j) {
    return j == 0 ? v.x : (j == 1 ? v.y : (j == 2 ? v.z : v.w));
}

__global__ void hybrid_main_k(
        const float* __restrict__ seg, const float* __restrict__ logits,
        const int* __restrict__ y, const int* __restrict__ wt,
        float* __restrict__ ws)
{
    const int b   = blockIdx.x & 1;       // interleave batches across XCDs
    const int blk = blockIdx.x >> 1;      // 0..511
    const int tid = threadIdx.x;

    __shared__ unsigned int shb[HCOPIES * HSTRIDE];   // 2592 B
    __shared__ float shred[20][4];

    for (int i = tid; i < HCOPIES * HSTRIDE; i += 256) shb[i] = 0u;
    __syncthreads();

    // weight==1 => (1-w)*L2 == 0 exactly; skip the logits stream (uniform,
    // deterministic branch: inputs restored before every launch).
    const bool need2 = (wt[0] != 1);

    const float4* s0 = (const float4*)seg + (size_t)(b * 4 + 0) * QB;
    const float4* s1 = (const float4*)seg + (size_t)(b * 4 + 1) * QB;
    const float4* s2 = (const float4*)seg + (size_t)(b * 4 + 2) * QB;
    const float4* s3 = (const float4*)seg + (size_t)(b * 4 + 3) * QB;
    const int4*   yq = (const int4*)y + (size_t)b * QB;

    // acc[0..3]=Sp, [4..7]=Spt1(one-hot), [8..11]=Cnt1(as float, exact),
    // [12..15]=St2(sigmoid), [16..19]=Spt2
    float acc[20];
    #pragma unroll
    for (int k = 0; k < 20; ++k) acc[k] = 0.0f;

    const float INV_STEP = 20.0f / (1.0f + 1e-8f);
    const int hbase = (tid & (HCOPIES - 1)) * HSTRIDE;
    const int q0 = blk * 256 + tid;

    // ---- software-pipelined loop: prefetch tile k+1 while computing k ----
    float4 cP0 = s0[q0], cP1 = s1[q0], cP2 = s2[q0], cP3 = s3[q0];
    int4   cY  = yq[q0];

    #pragma unroll
    for (int k = 0; k < KITER; ++k) {
        float4 nP0, nP1, nP2, nP3; int4 nY;
        if (k + 1 < KITER) {
            const int q = q0 + (k + 1) * QSTRIDE;
            nP0 = s0[q]; nP1 = s1[q]; nP2 = s2[q]; nP3 = s3[q]; nY = yq[q];
        }
        float4 G0, G1, G2, G3;
        if (need2) {
            const float4* l0 = (const float4*)logits + (size_t)(b * 4 + 0) * QB;
            const float4* l1 = (const float4*)logits + (size_t)(b * 4 + 1) * QB;
            const float4* l2 = (const float4*)logits + (size_t)(b * 4 + 2) * QB;
            const float4* l3 = (const float4*)logits + (size_t)(b * 4 + 3) * QB;
            const int q = q0 + k * QSTRIDE;
            G0 = l0[q]; G1 = l1[q]; G2 = l2[q]; G3 = l3[q];
        }

        #pragma unroll
        for (int j = 0; j < 4; ++j) {
            const float pv0 = sel(cP0, j), pv1 = sel(cP1, j);
            const float pv2 = sel(cP2, j), pv3 = sel(cP3, j);
            const int yj = seli(cY, j);

            acc[0] += pv0; acc[1] += pv1; acc[2] += pv2; acc[3] += pv3;
            acc[4] += (yj == 0) ? pv0 : 0.0f;
            acc[5] += (yj == 1) ? pv1 : 0.0f;
            acc[6] += (yj == 2) ? pv2 : 0.0f;
            acc[7] += (yj == 3) ? pv3 : 0.0f;
            acc[8]  += (yj == 0) ? 1.0f : 0.0f;
            acc[9]  += (yj == 1) ? 1.0f : 0.0f;
            acc[10] += (yj == 2) ? 1.0f : 0.0f;
            acc[11] += (yj == 3) ? 1.0f : 0.0f;

            if (need2) {
                const float sg0 = __fdividef(1.0f, 1.0f + __expf(-sel(G0, j)));
                const float sg1 = __fdividef(1.0f, 1.0f + __expf(-sel(G1, j)));
                const float sg2 = __fdividef(1.0f, 1.0f + __expf(-sel(G2, j)));
                const float sg3 = __fdividef(1.0f, 1.0f + __expf(-sel(G3, j)));
                acc[12] += sg0; acc[13] += sg1; acc[14] += sg2; acc[15] += sg3;
                acc[16] += pv0 * sg0; acc[17] += pv1 * sg1;
                acc[18] += pv2 * sg2; acc[19] += pv3 * sg3;
            }

            // softmax over channels (matches jax.nn.softmax: exp(x-max)/sum)
            const float mx = fmaxf(fmaxf(pv0, pv1), fmaxf(pv2, pv3));
            const float e0 = __expf(pv0 - mx), e1 = __expf(pv1 - mx);
            const float e2 = __expf(pv2 - mx), e3 = __expf(pv3 - mx);
            const float ssum = (e0 + e1) + (e2 + e3);
            const float pr1 = __fdividef(e1, ssum);
            const float pr2 = __fdividef(e2, ssum);
            int b1 = (int)(pr1 * INV_STEP); if (b1 > 19) b1 = 19;
            int b2 = (int)(pr2 * INV_STEP); if (b2 > 19) b2 = 19;
            atomicAdd(&shb[hbase + 20 + b1], 1u);   // class-1 total
            atomicAdd(&shb[hbase + 60 + b2], 1u);   // class-2 total
            if (yj == 1 || yj == 2) {               // mutually exclusive trues
                const int addr = (yj == 1) ? (hbase + b1) : (hbase + 40 + b2);
                atomicAdd(&shb[addr], 1u);
            }
        }
        cP0 = nP0; cP1 = nP1; cP2 = nP2; cP3 = nP3; cY = nY;
    }

    // ---- block reduction (all 20 rows: zero rows must still be WRITTEN,
    //      since there is no ws memset) ----
    #pragma unroll
    for (int k = 0; k < 20; ++k) {
        float v = acc[k];
        #pragma unroll
        for (int off = 32; off > 0; off >>= 1) v += __shfl_xor(v, off, 64);
        acc[k] = v;
    }
    const int wave = tid >> 6, lane = tid & 63;
    if (lane == 0) {
        #pragma unroll
        for (int k = 0; k < 20; ++k) shred[k][wave] = acc[k];
    }
    __syncthreads();

    // ---- private-slot plain stores (no atomics, no memset needed) ----
    if (tid < 20) {
        float t = shred[tid][0] + shred[tid][1] + shred[tid][2] + shred[tid][3];
        ws[(b * 20 + tid) * FSLOTS + blk] = t;
    }
    if (tid < 80) {
        unsigned int v = 0;
        #pragma unroll
        for (int c = 0; c < HCOPIES; ++c) v += shb[c * HSTRIDE + tid];
        ((unsigned int*)ws)[HB + tid * HSLOTS + blockIdx.x] = v;  // write 0s too
    }
}

__device__ __forceinline__ float fsigmoid(float x) {
    return __fdividef(1.0f, 1.0f + __expf(-x));
}

__device__ double dice_term(const double Sp[2], const double St[2], const double Spt[2],
                            double w0, double w1)
{
    const double sumP = Sp[0] + Sp[1], sumT = St[0] + St[1];
    const double u1 = sumP + sumT;
    const double u0 = (2.0 * (double)VB - sumP) + (2.0 * (double)VB - sumT);
    const double uni = w0 * u0 + w1 * u1;
    double dsum = 0.0;
    for (int b = 0; b < 2; ++b) {
        const double i1 = Spt[b];
        const double i0 = (double)VB - Sp[b] - St[b] + Spt[b];
        const double inter = w0 * i0 + w1 * i1;
        double dice = (2.0 * inter + 1.0) / (uni + 1.0);
        if (isnan(dice)) dice = 1.0;
        dsum += dice;
    }
    return 1.0 - 0.5 * dsum;
}

__global__ __launch_bounds__(256) void finalize_k(
        const float* __restrict__ ws, const float* __restrict__ calib,
        const int* __restrict__ wt, float* __restrict__ out)
{
    const int t = threadIdx.x;
    __shared__ float fsum[40];
    __shared__ unsigned int hsum[80];

    // Threads 0..39: reduce one float counter's 512 slots (float4-coalesced).
    if (t < 40) {
        const float4* p = (const float4*)(ws + t * FSLOTS);
        float s = 0.0f;
        #pragma unroll 4
        for (int i = 0; i < FSLOTS / 4; ++i) {
            const float4 v = p[i];
            s += (v.x + v.y) + (v.z + v.w);
        }
        fsum[t] = s;
    }
    // Threads 64..143: reduce one hist counter's 1024 slots (uint4-coalesced).
    if (t >= 64 && t < 144) {
        const int j = t - 64;
        const uint4* p = (const uint4*)((const unsigned int*)ws + HB + j * HSLOTS);
        unsigned int s = 0;
        #pragma unroll 4
        for (int i = 0; i < HSLOTS / 4; ++i) {
            const uint4 v = p[i];
            s += (v.x + v.y) + (v.z + v.w);
        }
        hsum[j] = s;
    }
    __syncthreads();
    if (t >= 64) return;

    // ECE terms: lanes 0..39 of wave 0, one (class, bin) cell each.
    float term = 0.0f;
    if (t < 40) {
        const int cc = t / NBINS, k = t % NBINS;
        const float bt   = fsigmoid((float)hsum[cc * 40 + k]);
        const float btot = fsigmoid((float)hsum[cc * 40 + 20 + k]);
        const float cal  = fsigmoid(calib[k * 4 + (cc + 1)]);
        const float d = cal - __fdividef(bt, btot);
        term = d * d;
    }
    #pragma unroll
    for (int off = 32; off > 0; off >>= 1) term += __shfl_xor(term, off, 64);

    if (t == 0) {
        const double means[4] = {0.03, 0.02, 0.01, 0.01};
        double L1 = 0.0, L2 = 0.0;
        for (int c = 0; c < 4; ++c) {
            const double mean = means[c];
            const double w1 = 1.0 / (mean * mean);
            const double w0 = 1.0 / ((1.0 - mean) * (1.0 - mean));
            double Sp[2], Spt1[2], C1[2], St2[2], Spt2[2];
            for (int b = 0; b < 2; ++b) {
                Sp[b]   = (double)fsum[b * 20 + 0 + c];
                Spt1[b] = (double)fsum[b * 20 + 4 + c];
                C1[b]   = (double)fsum[b * 20 + 8 + c];
                St2[b]  = (double)fsum[b * 20 + 12 + c];
                Spt2[b] = (double)fsum[b * 20 + 16 + c];
            }
            L1 += dice_term(Sp, C1, Spt1, w0, w1);
            L2 += dice_term(Sp, St2, Spt2, w0, w1);
        }
        L1 *= 0.2; L2 *= 0.2;   // sum of 4 channel losses / 5.0
        const double w = (double)wt[0];
        const double ece = (double)term / (double)NBINS;
        out[0] = (float)(w * L1 + (1.0 - w) * L2 + ece);
    }
}

extern "C" void kernel_launch(void* const* d_in, const int* in_sizes, int n_in,
                              void* d_out, int out_size, void* d_ws, size_t ws_size,
                              hipStream_t stream)
{
    const float* seg    = (const float*)d_in[0];
    const float* calib  = (const float*)d_in[1];
    const float* logits = (const float*)d_in[2];
    const int*   y      = (const int*)d_in[3];
    const int*   wt     = (const int*)d_in[4];
    float* ws  = (float*)d_ws;
    float* out = (float*)d_out;

    hipLaunchKernelGGL(hybrid_main_k, dim3(NBLK), dim3(256), 0, stream,
                       seg, logits, y, wt, ws);
    hipLaunchKernelGGL(finalize_k, dim3(1), dim3(256), 0, stream,
                       ws, calib, wt, out);
}